// Round 3
// baseline (608.447 us; speedup 1.0000x reference)
//
#include <hip/hip_runtime.h>
#include <hip/hip_bf16.h>
#include <stdint.h>

#define B_DIM 8192
#define IN_DIMC 1024
#define HIDC 1024
#define K_DIM 1024
#define ODE_STEPS 6

typedef float f32x4 __attribute__((ext_vector_type(4)));
typedef float f32x16 __attribute__((ext_vector_type(16)));
typedef short bf16x8 __attribute__((ext_vector_type(8)));

__device__ __forceinline__ float bf2f(unsigned short u) {
    union { unsigned int u; float f; } c; c.u = ((unsigned int)u) << 16; return c.f;
}
__device__ __forceinline__ unsigned short f2bf(float f) {
    union { float f; unsigned int u; } c; c.f = f;
    unsigned int u = c.u;
    return (unsigned short)((u + 0x7fffu + ((u >> 16) & 1u)) >> 16);
}
__device__ __forceinline__ float fast_tanh(float x) {
    float e = __expf(2.0f * x);
    return 1.0f - 2.0f / (e + 1.0f);
}

// ---------------- convert all f32 inputs to bf16 in workspace ----------------
constexpr size_t XN    = (size_t)B_DIM * IN_DIMC;
constexpr size_t HN    = (size_t)B_DIM * HIDC;
constexpr size_t WINN  = (size_t)HIDC * IN_DIMC;
constexpr size_t WRECN = (size_t)HIDC * HIDC;
constexpr size_t WGN   = (size_t)HIDC * (IN_DIMC + HIDC);
constexpr size_t TOTQ  = (XN + HN + WINN + WRECN + WGN) / 4;

__global__ __launch_bounds__(256) void convert_all(
    const float* __restrict__ x, const float* __restrict__ h,
    const float* __restrict__ win, const float* __restrict__ wrec,
    const float* __restrict__ wgate,
    unsigned short* __restrict__ x_bf, unsigned short* __restrict__ h_bf,
    unsigned short* __restrict__ win_bf, unsigned short* __restrict__ wrec_bf,
    unsigned short* __restrict__ wgx_bf, unsigned short* __restrict__ wgh_bf)
{
    size_t q = (size_t)blockIdx.x * 256 + threadIdx.x;
    if (q >= TOTQ) return;
    size_t e = q * 4;
    const float* src; unsigned short* dst; size_t si, di;
    if (e < XN)                          { src = x;    si = e;                       dst = x_bf;    di = si; }
    else if (e < XN + HN)                { src = h;    si = e - XN;                  dst = h_bf;    di = si; }
    else if (e < XN + HN + WINN)         { src = win;  si = e - XN - HN;             dst = win_bf;  di = si; }
    else if (e < XN + HN + WINN + WRECN) { src = wrec; si = e - XN - HN - WINN;      dst = wrec_bf; di = si; }
    else {
        size_t i = e - XN - HN - WINN - WRECN;
        size_t row = i >> 11, col = i & 2047;
        src = wgate; si = i;
        if (col < 1024) { dst = wgx_bf; di = row * 1024 + col; }
        else            { dst = wgh_bf; di = row * 1024 + (col - 1024); }
    }
    float4 v = *(const float4*)(src + si);
    ushort4 o;
    o.x = f2bf(v.x); o.y = f2bf(v.y); o.z = f2bf(v.z); o.w = f2bf(v.w);
    *(ushort4*)(dst + di) = o;
}

// ------- fused dual-GEMM: 32x32x16 MFMA, BM=128 BN=64 BK=64, xor-swizzled LDS
constexpr int BM = 128, BN = 64, BK = 64;
constexpr int NT = HIDC / BN; // 16

__device__ __forceinline__ void gload_lds16(const void* g, void* l) {
    __builtin_amdgcn_global_load_lds(
        (const __attribute__((address_space(1))) void*)g,
        (__attribute__((address_space(3))) void*)l, 16, 0, 0);
}

template<bool STEP>
__global__ __launch_bounds__(256, 3) void ltc_gemm(
    const unsigned short* __restrict__ A,
    const unsigned short* __restrict__ B1,
    const unsigned short* __restrict__ B2,
    const unsigned short* __restrict__ GX, const unsigned short* __restrict__ ID,
    const float* __restrict__ h_in, const float* __restrict__ log_tau,
    float* __restrict__ h_out, float* __restrict__ h_out2,
    unsigned short* __restrict__ hbf_out,
    const float* __restrict__ bias1, const float* __restrict__ bias2,
    unsigned short* __restrict__ GX_out, unsigned short* __restrict__ ID_out)
{
    __shared__ __attribute__((aligned(16))) unsigned short lA[BM * BK];   // 16 KB
    __shared__ __attribute__((aligned(16))) unsigned short lB1[BN * BK];  // 8 KB
    __shared__ __attribute__((aligned(16))) unsigned short lB2[BN * BK];  // 8 KB

    const int tid = threadIdx.x;
    const int w = tid >> 6, l = tid & 63;
    const int mt = blockIdx.x / NT, nt = blockIdx.x % NT;
    const int m0 = mt * BM, n0 = nt * BN;
    const int wm = (w >> 1) * 64, wn = (w & 1) * 32;

    // staging: each instr = 8 rows x 128B; lane l -> row l>>3, swizzled chunk
    const int srow8 = l >> 3;                       // 0..7
    const int scol  = ((l & 7) ^ srow8) * 8;        // xor-swizzled element col

    // fragment read indices
    const int lr = l & 31, lh = l >> 5;
    const int rsw = lr & 7;                         // row-based xor key

    f32x16 acc1[2], acc2[2];
    #pragma unroll
    for (int i = 0; i < 2; i++) {
        acc1[i] = (f32x16)0.0f;
        acc2[i] = (f32x16)0.0f;
    }

    for (int k0 = 0; k0 < K_DIM; k0 += BK) {
        // A: 4 instrs/wave (rows w*32 .. +32), B1/B2: 2 each (rows w*16 .. +16)
        #pragma unroll
        for (int i = 0; i < 4; i++) {
            int R = w * 32 + i * 8;
            gload_lds16(A + (size_t)(m0 + R + srow8) * K_DIM + k0 + scol, &lA[R * BK]);
        }
        #pragma unroll
        for (int i = 0; i < 2; i++) {
            int R = w * 16 + i * 8;
            gload_lds16(B1 + (size_t)(n0 + R + srow8) * K_DIM + k0 + scol, &lB1[R * BK]);
            gload_lds16(B2 + (size_t)(n0 + R + srow8) * K_DIM + k0 + scol, &lB2[R * BK]);
        }
        __syncthreads();

        #pragma unroll
        for (int kc = 0; kc < 4; kc++) {
            const int csw = ((kc * 2 + lh) ^ rsw) * 8;
            bf16x8 b1f = *(const bf16x8*)&lB1[(wn + lr) * BK + csw];
            bf16x8 b2f = *(const bf16x8*)&lB2[(wn + lr) * BK + csw];
            #pragma unroll
            for (int mi = 0; mi < 2; mi++) {
                bf16x8 af = *(const bf16x8*)&lA[(wm + mi * 32 + lr) * BK + csw];
                acc1[mi] = __builtin_amdgcn_mfma_f32_32x32x16_bf16(af, b1f, acc1[mi], 0, 0, 0);
                acc2[mi] = __builtin_amdgcn_mfma_f32_32x32x16_bf16(af, b2f, acc2[mi], 0, 0, 0);
            }
        }
        __syncthreads();
    }

    // epilogue: 32x32 C/D layout col=lane&31, row=(reg&3)+8*(reg>>2)+4*(lane>>5)
    constexpr float subdt = 1.0f / (float)ODE_STEPS;
    const int gn = n0 + wn + lr;
    float sc = 0.f, b1 = 0.f, b2 = 0.f;
    if (STEP) sc = subdt * __expf(-log_tau[gn]);
    else { b1 = bias1[gn]; b2 = bias2[gn]; }

    #pragma unroll
    for (int mi = 0; mi < 2; mi++) {
        const int rbase = m0 + wm + mi * 32 + 4 * lh;
        #pragma unroll
        for (int g = 0; g < 4; g++) {
            #pragma unroll
            for (int r = 0; r < 4; r++) {
                const int grow = rbase + r + 8 * g;
                const size_t idx = (size_t)grow * HIDC + gn;
                const float v1 = acc1[mi][g * 4 + r];
                const float v2 = acc2[mi][g * 4 + r];
                if (STEP) {
                    float gx = bf2f(GX[idx]) + v1;
                    float dr = bf2f(ID[idx]) + v2;
                    float gt = fast_tanh(dr) / (1.0f + __expf(-gx));
                    float hv = h_in[idx];
                    float hn = fmaf(sc, gt - hv, hv);
                    h_out[idx] = hn;
                    hbf_out[idx] = f2bf(hn);
                    if (h_out2) h_out2[idx] = hn;
                } else {
                    GX_out[idx] = f2bf(v1 + b1);
                    ID_out[idx] = f2bf(v2 + b2);
                }
            }
        }
    }
}

extern "C" void kernel_launch(void* const* d_in, const int* in_sizes, int n_in,
                              void* d_out, int out_size, void* d_ws, size_t ws_size,
                              hipStream_t stream)
{
    const float* x    = (const float*)d_in[0];
    const float* h    = (const float*)d_in[1];
    const float* ltau = (const float*)d_in[2];
    const float* winw = (const float*)d_in[3];
    const float* winb = (const float*)d_in[4];
    const float* wrec = (const float*)d_in[5];
    const float* wg   = (const float*)d_in[6];
    const float* wgb  = (const float*)d_in[7];

    char* ws = (char*)d_ws;
    unsigned short* x_bf    = (unsigned short*)ws; ws += XN * 2;
    unsigned short* h_bf0   = (unsigned short*)ws; ws += HN * 2;
    unsigned short* h_bf1   = (unsigned short*)ws; ws += HN * 2;
    unsigned short* win_bf  = (unsigned short*)ws; ws += WINN * 2;
    unsigned short* wrec_bf = (unsigned short*)ws; ws += WRECN * 2;
    unsigned short* wgx_bf  = (unsigned short*)ws; ws += WINN * 2;
    unsigned short* wgh_bf  = (unsigned short*)ws; ws += WRECN * 2;
    unsigned short* GXb     = (unsigned short*)ws; ws += HN * 2;
    unsigned short* IDb     = (unsigned short*)ws; ws += HN * 2;

    float* hout  = (float*)d_out;
    float* hout2 = hout + (size_t)B_DIM * HIDC;

    convert_all<<<(int)(TOTQ / 256), 256, 0, stream>>>(
        x, h, winw, wrec, wg, x_bf, h_bf0, win_bf, wrec_bf, wgx_bf, wgh_bf);

    const int grid = (B_DIM / BM) * NT; // 1024
    ltc_gemm<false><<<grid, 256, 0, stream>>>(
        x_bf, wgx_bf, win_bf,
        nullptr, nullptr, nullptr, nullptr, nullptr, nullptr, nullptr,
        wgb, winb, GXb, IDb);

    unsigned short* hbf[2] = {h_bf0, h_bf1};
    for (int s = 0; s < ODE_STEPS; s++) {
        const float* hin = (s == 0) ? h : (const float*)hout;
        float* o2 = (s == ODE_STEPS - 1) ? hout2 : nullptr;
        ltc_gemm<true><<<grid, 256, 0, stream>>>(
            hbf[s & 1], wgh_bf, wrec_bf,
            GXb, IDb, hin, ltau, hout, o2, hbf[(s + 1) & 1],
            nullptr, nullptr, nullptr, nullptr);
    }
}

// Round 4
// 521.148 us; speedup vs baseline: 1.1675x; 1.1675x over previous
//
#include <hip/hip_runtime.h>
#include <hip/hip_bf16.h>
#include <stdint.h>

#define B_DIM 8192
#define IN_DIMC 1024
#define HIDC 1024
#define K_DIM 1024
#define ODE_STEPS 6

typedef float f32x4 __attribute__((ext_vector_type(4)));
typedef short bf16x8 __attribute__((ext_vector_type(8)));
typedef unsigned short u16x8 __attribute__((ext_vector_type(8)));

__device__ __forceinline__ float bf2f(unsigned short u) {
    union { unsigned int u; float f; } c; c.u = ((unsigned int)u) << 16; return c.f;
}
__device__ __forceinline__ unsigned short f2bf(float f) {
    union { float f; unsigned int u; } c; c.f = f;
    unsigned int u = c.u;
    return (unsigned short)((u + 0x7fffu + ((u >> 16) & 1u)) >> 16);
}
__device__ __forceinline__ float fast_tanh(float x) {
    float e = __expf(2.0f * x);
    return 1.0f - 2.0f / (e + 1.0f);
}

// ---------------- convert all f32 inputs to bf16 in workspace ----------------
constexpr size_t XN    = (size_t)B_DIM * IN_DIMC;
constexpr size_t HN    = (size_t)B_DIM * HIDC;
constexpr size_t WINN  = (size_t)HIDC * IN_DIMC;
constexpr size_t WRECN = (size_t)HIDC * HIDC;
constexpr size_t WGN   = (size_t)HIDC * (IN_DIMC + HIDC);
constexpr size_t TOTQ  = (XN + HN + WINN + WRECN + WGN) / 4;

__global__ __launch_bounds__(256) void convert_all(
    const float* __restrict__ x, const float* __restrict__ h,
    const float* __restrict__ win, const float* __restrict__ wrec,
    const float* __restrict__ wgate,
    unsigned short* __restrict__ x_bf, unsigned short* __restrict__ h_bf,
    unsigned short* __restrict__ win_bf, unsigned short* __restrict__ wrec_bf,
    unsigned short* __restrict__ wgx_bf, unsigned short* __restrict__ wgh_bf)
{
    size_t q = (size_t)blockIdx.x * 256 + threadIdx.x;
    if (q >= TOTQ) return;
    size_t e = q * 4;
    const float* src; unsigned short* dst; size_t si, di;
    if (e < XN)                          { src = x;    si = e;                       dst = x_bf;    di = si; }
    else if (e < XN + HN)                { src = h;    si = e - XN;                  dst = h_bf;    di = si; }
    else if (e < XN + HN + WINN)         { src = win;  si = e - XN - HN;             dst = win_bf;  di = si; }
    else if (e < XN + HN + WINN + WRECN) { src = wrec; si = e - XN - HN - WINN;      dst = wrec_bf; di = si; }
    else {
        size_t i = e - XN - HN - WINN - WRECN;
        size_t row = i >> 11, col = i & 2047;
        src = wgate; si = i;
        if (col < 1024) { dst = wgx_bf; di = row * 1024 + col; }
        else            { dst = wgh_bf; di = row * 1024 + (col - 1024); }
    }
    float4 v = *(const float4*)(src + si);
    ushort4 o;
    o.x = f2bf(v.x); o.y = f2bf(v.y); o.z = f2bf(v.z); o.w = f2bf(v.w);
    *(ushort4*)(dst + di) = o;
}

// ---- fused dual-GEMM, R1 core (16x16x32, BM=128 BN=64 BK=32, 3 blk/CU) ----
// Epilogue state (GX/ID bf16, carried h f32) lives in "accumulator-native"
// layout: slot = ((block*4 + wave)*8 + mi*2+ni)*64 + lane; 16B per lane per
// (mi,ni) -> every state access is a full-line 1KB/instr transaction.
constexpr int BM = 128, BN = 64, BK = 32;
constexpr int NT = HIDC / BN; // 16

__device__ __forceinline__ void gload_lds16(const void* g, void* l) {
    __builtin_amdgcn_global_load_lds(
        (const __attribute__((address_space(1))) void*)g,
        (__attribute__((address_space(3))) void*)l, 16, 0, 0);
}

template<bool STEP>
__global__ __launch_bounds__(256, 3) void ltc_gemm(
    const unsigned short* __restrict__ A,
    const unsigned short* __restrict__ B1,
    const unsigned short* __restrict__ B2,
    const unsigned short* __restrict__ GXID,   // native layout, 8 bf16/slot
    const float* __restrict__ h_init,          // row-major f32 (step 0 only)
    float* __restrict__ h_nat,                 // native f32 state, in-place
    const float* __restrict__ log_tau,
    float* __restrict__ h_out,                 // final step: d_out half 0
    float* __restrict__ h_out2,                // final step: d_out half 1
    unsigned short* __restrict__ hbf_out,      // row-major bf16 (next A)
    const float* __restrict__ bias1, const float* __restrict__ bias2,
    unsigned short* __restrict__ GXID_out)     // pre-kernel output
{
    __shared__ __attribute__((aligned(16))) unsigned short lA[BM * BK];   // 8 KB
    __shared__ __attribute__((aligned(16))) unsigned short lB1[BN * BK];  // 4 KB
    __shared__ __attribute__((aligned(16))) unsigned short lB2[BN * BK];  // 4 KB

    const int tid = threadIdx.x;
    const int w = tid >> 6, l = tid & 63;
    const int mt = blockIdx.x / NT, nt = blockIdx.x % NT;
    const int m0 = mt * BM, n0 = nt * BN;
    const int wm = (w >> 1) * 64, wn = (w & 1) * 32;
    const int lrow = l >> 2, lcol = (l & 3) * 8;
    const int lm = l & 15, lq = l >> 4;

    f32x4 acc1[4][2], acc2[4][2];
    f32x4 z4 = {0.f, 0.f, 0.f, 0.f};
    #pragma unroll
    for (int i = 0; i < 4; i++)
        #pragma unroll
        for (int j = 0; j < 2; j++) { acc1[i][j] = z4; acc2[i][j] = z4; }

    const int arow = w * 32;
    const unsigned short* Bsrc = (w < 2) ? B1 : B2;
    unsigned short* lBdst = (w < 2) ? lB1 : lB2;
    const int brow = (w & 1) * 32;

    for (int k0 = 0; k0 < K_DIM; k0 += BK) {
        #pragma unroll
        for (int i = 0; i < 2; i++) {
            int ra = arow + i * 16;
            int rb = brow + i * 16;
            gload_lds16(A    + (size_t)(m0 + ra + lrow) * K_DIM + k0 + lcol, &lA[ra * BK]);
            gload_lds16(Bsrc + (size_t)(n0 + rb + lrow) * K_DIM + k0 + lcol, &lBdst[rb * BK]);
        }
        __syncthreads();

        bf16x8 af[4], f1[2], f2[2];
        #pragma unroll
        for (int mi = 0; mi < 4; mi++)
            af[mi] = *(const bf16x8*)&lA[(wm + mi * 16 + lm) * BK + lq * 8];
        #pragma unroll
        for (int ni = 0; ni < 2; ni++) {
            f1[ni] = *(const bf16x8*)&lB1[(wn + ni * 16 + lm) * BK + lq * 8];
            f2[ni] = *(const bf16x8*)&lB2[(wn + ni * 16 + lm) * BK + lq * 8];
        }
        #pragma unroll
        for (int mi = 0; mi < 4; mi++)
            #pragma unroll
            for (int ni = 0; ni < 2; ni++) {
                acc1[mi][ni] = __builtin_amdgcn_mfma_f32_16x16x32_bf16(af[mi], f1[ni], acc1[mi][ni], 0, 0, 0);
                acc2[mi][ni] = __builtin_amdgcn_mfma_f32_16x16x32_bf16(af[mi], f2[ni], acc2[mi][ni], 0, 0, 0);
            }
        __syncthreads();
    }

    // epilogue: C/D layout col=lane&15, row=(lane>>4)*4+r  [m89-verified]
    constexpr float subdt = 1.0f / (float)ODE_STEPS;
    const size_t wslot = (((size_t)blockIdx.x * 4 + w) * 8) * 64 + l;

    #pragma unroll
    for (int mi = 0; mi < 4; mi++) {
        #pragma unroll
        for (int ni = 0; ni < 2; ni++) {
            const int gmb = m0 + wm + mi * 16 + lq * 4;
            const int gn  = n0 + wn + ni * 16 + lm;
            const size_t slot = wslot + (size_t)(mi * 2 + ni) * 64;
            if (STEP) {
                const float sc = subdt * __expf(-log_tau[gn]);
                u16x8 gi = *(const u16x8*)&GXID[slot * 8];
                f32x4 st;
                if (h_init) {
                    #pragma unroll
                    for (int r = 0; r < 4; r++)
                        st[r] = h_init[(size_t)(gmb + r) * HIDC + gn];
                } else {
                    st = *(const f32x4*)&h_nat[slot * 4];
                }
                f32x4 hn;
                #pragma unroll
                for (int r = 0; r < 4; r++) {
                    float gx = bf2f((unsigned short)gi[r])     + acc1[mi][ni][r];
                    float dr = bf2f((unsigned short)gi[4 + r]) + acc2[mi][ni][r];
                    float gt = fast_tanh(dr) / (1.0f + __expf(-gx));
                    hn[r] = fmaf(sc, gt - st[r], st[r]);
                }
                if (h_out) {
                    #pragma unroll
                    for (int r = 0; r < 4; r++) {
                        size_t idx = (size_t)(gmb + r) * HIDC + gn;
                        h_out[idx]  = hn[r];
                        h_out2[idx] = hn[r];
                    }
                } else {
                    *(f32x4*)&h_nat[slot * 4] = hn;
                    #pragma unroll
                    for (int r = 0; r < 4; r++)
                        hbf_out[(size_t)(gmb + r) * HIDC + gn] = f2bf(hn[r]);
                }
            } else {
                const float b1 = bias1[gn], b2 = bias2[gn];
                u16x8 o;
                #pragma unroll
                for (int r = 0; r < 4; r++) {
                    o[r]     = f2bf(acc1[mi][ni][r] + b1);
                    o[4 + r] = f2bf(acc2[mi][ni][r] + b2);
                }
                *(u16x8*)&GXID_out[slot * 8] = o;
            }
        }
    }
}

extern "C" void kernel_launch(void* const* d_in, const int* in_sizes, int n_in,
                              void* d_out, int out_size, void* d_ws, size_t ws_size,
                              hipStream_t stream)
{
    const float* x    = (const float*)d_in[0];
    const float* h    = (const float*)d_in[1];
    const float* ltau = (const float*)d_in[2];
    const float* winw = (const float*)d_in[3];
    const float* winb = (const float*)d_in[4];
    const float* wrec = (const float*)d_in[5];
    const float* wg   = (const float*)d_in[6];
    const float* wgb  = (const float*)d_in[7];

    char* ws = (char*)d_ws;
    unsigned short* x_bf    = (unsigned short*)ws; ws += XN * 2;
    unsigned short* h_bf0   = (unsigned short*)ws; ws += HN * 2;
    unsigned short* h_bf1   = (unsigned short*)ws; ws += HN * 2;
    unsigned short* win_bf  = (unsigned short*)ws; ws += WINN * 2;
    unsigned short* wrec_bf = (unsigned short*)ws; ws += WRECN * 2;
    unsigned short* wgx_bf  = (unsigned short*)ws; ws += WINN * 2;
    unsigned short* wgh_bf  = (unsigned short*)ws; ws += WRECN * 2;
    unsigned short* GXID    = (unsigned short*)ws; ws += HN * 2 * 2;  // 32 MB
    float*          h_nat   = (float*)ws;          ws += HN * 4;      // 32 MB

    float* hout  = (float*)d_out;
    float* hout2 = hout + (size_t)B_DIM * HIDC;

    convert_all<<<(int)(TOTQ / 256), 256, 0, stream>>>(
        x, h, winw, wrec, wg, x_bf, h_bf0, win_bf, wrec_bf, wgx_bf, wgh_bf);

    const int grid = (B_DIM / BM) * NT; // 1024
    // pre-loop: GXID = pack(x@Wgx^T + wgb, x@Win^T + winb) in native layout
    ltc_gemm<false><<<grid, 256, 0, stream>>>(
        x_bf, wgx_bf, win_bf,
        nullptr, nullptr, nullptr, nullptr, nullptr, nullptr, nullptr,
        wgb, winb, GXID);

    unsigned short* hbf[2] = {h_bf0, h_bf1};
    for (int s = 0; s < ODE_STEPS; s++) {
        const bool last = (s == ODE_STEPS - 1);
        ltc_gemm<true><<<grid, 256, 0, stream>>>(
            hbf[s & 1], wgh_bf, wrec_bf,
            GXID,
            (s == 0) ? h : nullptr,
            h_nat, ltau,
            last ? hout : nullptr, last ? hout2 : nullptr,
            last ? nullptr : hbf[(s + 1) & 1],
            nullptr, nullptr, nullptr);
    }
}